// Round 7
// baseline (39.562 us; speedup 1.0000x reference)
//
#include <hip/hip_runtime.h>

// 5x5 median, reflect padding, NHWC f32 (16,384,384,3).
// Interior thread = 2 flat columns (f, f+1; f even) x RUN=8 rows.
// ALL interior state in NAMED SCALARS (no arrays, no pointer-passed helpers):
// R2-R6 showed VGPR_Count far below live-state size -> compiler demoted the
// ring to scratch (L2-resident, invisible in FETCH_SIZE, ~200cy latencies,
// VALUBusy stuck at ~61%). Macro-only network forces register residency.
//   - Taps for flat col f at stride C=3: {f-6,f-3,f,f+3,f+6}; pair spans
//     14 floats = 7 aligned float2 loads per row.
//   - Ring of 5 sorted 5-windows per column, hard-coded slot rotation.
//   - MED25: SORT4 of 4 old rows + closed-form rank-insert of new row
//     (13 band cells) + forgetful rank-7-of-13. [validated R2-R6]
// Border columns (flat 0..5, 1146..1151) in dedicated trailing blocks.

#define CAS(a, b) do { float _t = fminf(a, b); (b) = fmaxf(a, b); (a) = _t; } while (0)

#define SORT5(e0, e1, e2, e3, e4) do { \
  CAS(e0, e1); CAS(e3, e4); CAS(e2, e4); CAS(e2, e3); CAS(e1, e4); \
  CAS(e0, e3); CAS(e0, e2); CAS(e1, e3); CAS(e1, e2); } while (0)

#define SORT4(a, b, c, d) do { \
  CAS(a, b); CAS(c, d); CAS(a, c); CAS(b, d); CAS(b, c); } while (0)

__device__ __forceinline__ int reflect_idx(int v, int n) {
  v = v < 0 ? -v : v;
  v = v >= n ? 2 * n - 2 - v : v;
  return v;
}

// Sort 5 locals and store into ring slot P (P##0..P##4).
#define SORT_TO(P, e0, e1, e2, e3, e4) do { \
  SORT5(e0, e1, e2, e3, e4); \
  P##0 = e0; P##1 = e1; P##2 = e2; P##3 = e3; P##4 = e4; } while (0)

// Exact median of 25 from sorted rows SA..SD (older, any order) + SN (newest).
#define MED25(dst, SA, SB, SC, SD, SN) do { \
  float A1, A2, B1, B2, B3, Cx1, Cx2, Cx3, D1, D2, D3, E1, E2; \
  { float p=SA##0,q=SB##0,r=SC##0,s=SD##0,e=SN##0; SORT4(p,q,r,s); \
    D1 = fmaxf(r, fminf(s, e)); E1 = fmaxf(s, e); } \
  { float p=SA##1,q=SB##1,r=SC##1,s=SD##1,e=SN##1; SORT4(p,q,r,s); \
    Cx1 = fmaxf(q, fminf(r, e)); D2 = fmaxf(r, fminf(s, e)); E2 = fmaxf(s, e); } \
  { float p=SA##2,q=SB##2,r=SC##2,s=SD##2,e=SN##2; SORT4(p,q,r,s); \
    B1 = fmaxf(p, fminf(q, e)); Cx2 = fmaxf(q, fminf(r, e)); D3 = fmaxf(r, fminf(s, e)); } \
  { float p=SA##3,q=SB##3,r=SC##3,s=SD##3,e=SN##3; SORT4(p,q,r,s); \
    A1 = fminf(p, e); B2 = fminf(q, fmaxf(p, e)); Cx3 = fminf(r, fmaxf(q, e)); } \
  { float p=SA##4,q=SB##4,r=SC##4,s=SD##4,e=SN##4; SORT4(p,q,r,s); \
    A2 = fminf(p, e); B3 = fminf(q, fmaxf(p, e)); } \
  CAS(B3, Cx3); CAS(A1, B1); CAS(A1, Cx1); \
  CAS(A2, B3); CAS(Cx2, D2); CAS(B3, D2); \
  CAS(B1, Cx1); CAS(D1, A2); CAS(B1, D1); \
  { float s0=Cx1,s1=B2,s2=B3,s3=Cx2,s4=A2,s5=D1,s6=D3,s7=E1; \
    CAS(s0, s1); CAS(s2, s3); CAS(s4, s5); CAS(s6, s7); \
    CAS(s0, s2); CAS(s4, s6); CAS(s0, s4); \
    CAS(s1, s3); CAS(s5, s7); CAS(s3, s7); \
    float t0=s1,t1=s2,t2=s3,t3=s4,t4=s5,t5=s6,t6=E2; \
    CAS(t0, t1); CAS(t2, t3); CAS(t4, t5); \
    CAS(t0, t2); CAS(t0, t4); CAS(t0, t6); \
    CAS(t1, t3); CAS(t5, t6); CAS(t3, t6); \
    CAS(t1, t2); CAS(t3, t4); \
    CAS(t1, t3); CAS(t1, t5); \
    CAS(t2, t4); CAS(t4, t5); \
    CAS(t2, t3); \
    dst = fmaxf(t2, fminf(t3, t4)); } \
} while (0)

constexpr int RUN = 8;
constexpr int Bn = 16, Hn = 384, Wn = 384, Cn = 3;
constexpr int WC = Wn * Cn;              // 1152
constexpr int HB = Hn / RUN;             // 48
constexpr int NG_I = 570;                // pairs (f, f+1), f = 6 + 2*gi
constexpr int N_INT = Bn * HB * NG_I;    // 437760 = 1710 * 256
constexpr int N_BND = Bn * HB * 12;      // 9216   = 36 * 256

// Prologue row -> slots AN/BN (uses local w* so prefetch v* stays untouched).
#define PROLOG(P, AN, BN) do { \
  const float2* rp = reinterpret_cast<const float2*>(xb + reflect_idx(h0 - 2 + (P), Hn) * WC); \
  float2 w0=rp[0],w1=rp[1],w2=rp[2],w3=rp[3],w4=rp[4],w5=rp[5],w6=rp[6]; \
  float e0=w0.x,e1=w1.y,e2=w3.x,e3=w4.y,e4=w6.x; \
  float g0=w0.y,g1=w2.x,g2=w3.y,g3=w5.x,g4=w6.y; \
  SORT_TO(AN, e0, e1, e2, e3, e4); \
  SORT_TO(BN, g0, g1, g2, g3, g4); \
} while (0)

// One output row: consume prefetch v0..v6 into slot AN/BN, issue next
// prefetch, compute both medians, float2 store.
#define PHASE(K, AN, AO0, AO1, AO2, AO3, BN, BO0, BO1, BO2, BO3) do { \
  float e0=v0.x,e1=v1.y,e2=v3.x,e3=v4.y,e4=v6.x; \
  float g0=v0.y,g1=v2.x,g2=v3.y,g3=v5.x,g4=v6.y; \
  SORT_TO(AN, e0, e1, e2, e3, e4); \
  SORT_TO(BN, g0, g1, g2, g3, g4); \
  if ((K) + 1 < RUN) { \
    const float2* rp = reinterpret_cast<const float2*>(xb + reflect_idx(h0 + (K) + 3, Hn) * WC); \
    v0=rp[0]; v1=rp[1]; v2=rp[2]; v3=rp[3]; v4=rp[4]; v5=rp[5]; v6=rp[6]; \
  } \
  float2 ov; \
  MED25(ov.x, AO0, AO1, AO2, AO3, AN); \
  MED25(ov.y, BO0, BO1, BO2, BO3, BN); \
  *reinterpret_cast<float2*>(out + orow + (K) * WC) = ov; \
} while (0)

__global__ __launch_bounds__(256) void median5x5_kernel(
    const float* __restrict__ x, float* __restrict__ out) {
  int t = blockIdx.x * blockDim.x + threadIdx.x;

  if (t < N_INT) {
    // ---------------- interior fast path (named scalars only) ----------------
    int gi = t % NG_I;
    int rest = t / NG_I;
    int hb = rest % HB;
    int b = rest / HB;
    int h0 = hb * RUN;
    int f = 6 + 2 * gi;

    const float* xb = x + b * Hn * WC + (f - 6);

    // ring: col a (flat f) and col b (flat f+1), 5 slots x 5 sorted elems
    float a00,a01,a02,a03,a04, a10,a11,a12,a13,a14, a20,a21,a22,a23,a24,
          a30,a31,a32,a33,a34, a40,a41,a42,a43,a44;
    float b00,b01,b02,b03,b04, b10,b11,b12,b13,b14, b20,b21,b22,b23,b24,
          b30,b31,b32,b33,b34, b40,b41,b42,b43,b44;

    PROLOG(0, a0, b0);
    PROLOG(1, a1, b1);
    PROLOG(2, a2, b2);
    PROLOG(3, a3, b3);

    // prefetch first compute row (h0+2)
    float2 v0, v1, v2, v3, v4, v5, v6;
    {
      const float2* rp = reinterpret_cast<const float2*>(xb + reflect_idx(h0 + 2, Hn) * WC);
      v0=rp[0]; v1=rp[1]; v2=rp[2]; v3=rp[3]; v4=rp[4]; v5=rp[5]; v6=rp[6];
    }

    int orow = (b * Hn + h0) * WC + f;

    PHASE(0, a4, a0,a1,a2,a3,  b4, b0,b1,b2,b3);
    PHASE(1, a0, a1,a2,a3,a4,  b0, b1,b2,b3,b4);
    PHASE(2, a1, a2,a3,a4,a0,  b1, b2,b3,b4,b0);
    PHASE(3, a2, a3,a4,a0,a1,  b2, b3,b4,b0,b1);
    PHASE(4, a3, a4,a0,a1,a2,  b3, b4,b0,b1,b2);
    PHASE(5, a4, a0,a1,a2,a3,  b4, b0,b1,b2,b3);
    PHASE(6, a0, a1,a2,a3,a4,  b0, b1,b2,b3,b4);
    PHASE(7, a1, a2,a3,a4,a0,  b1, b2,b3,b4,b0);
  } else {
    // ---------------- border columns (w reflection), named scalars too -------
    int u = t - N_INT;
    int col = u % 12;
    int rest = u / 12;
    int hb = rest % HB;
    int b = rest / HB;
    int h0 = hb * RUN;
    int f = col < 6 ? col : (WC - 12 + col);   // 0..5 or 1146..1151
    int w = f / 3, c = f % 3;

    int o0 = reflect_idx(w - 2, Wn) * 3 + c;
    int o1 = reflect_idx(w - 1, Wn) * 3 + c;
    int o2 = w * 3 + c;
    int o3 = reflect_idx(w + 1, Wn) * 3 + c;
    int o4 = reflect_idx(w + 2, Wn) * 3 + c;

    const float* xb = x + b * Hn * WC;

    float a00,a01,a02,a03,a04, a10,a11,a12,a13,a14, a20,a21,a22,a23,a24,
          a30,a31,a32,a33,a34, a40,a41,a42,a43,a44;

#define BPROLOG(P, AN) do { \
    const float* rp = xb + reflect_idx(h0 - 2 + (P), Hn) * WC; \
    float e0=rp[o0], e1=rp[o1], e2=rp[o2], e3=rp[o3], e4=rp[o4]; \
    SORT_TO(AN, e0, e1, e2, e3, e4); } while (0)

    BPROLOG(0, a0); BPROLOG(1, a1); BPROLOG(2, a2); BPROLOG(3, a3);

    int orow = (b * Hn + h0) * WC + f;

#define BPHASE(K, AN, AO0, AO1, AO2, AO3) do { \
    const float* rp = xb + reflect_idx(h0 + (K) + 2, Hn) * WC; \
    float e0=rp[o0], e1=rp[o1], e2=rp[o2], e3=rp[o3], e4=rp[o4]; \
    SORT_TO(AN, e0, e1, e2, e3, e4); \
    float om; \
    MED25(om, AO0, AO1, AO2, AO3, AN); \
    out[orow + (K) * WC] = om; } while (0)

    BPHASE(0, a4, a0,a1,a2,a3);
    BPHASE(1, a0, a1,a2,a3,a4);
    BPHASE(2, a1, a2,a3,a4,a0);
    BPHASE(3, a2, a3,a4,a0,a1);
    BPHASE(4, a3, a4,a0,a1,a2);
    BPHASE(5, a4, a0,a1,a2,a3);
    BPHASE(6, a0, a1,a2,a3,a4);
    BPHASE(7, a1, a2,a3,a4,a0);
  }
}

extern "C" void kernel_launch(void* const* d_in, const int* in_sizes, int n_in,
                              void* d_out, int out_size, void* d_ws, size_t ws_size,
                              hipStream_t stream) {
  const float* x = (const float*)d_in[0];
  float* out = (float*)d_out;
  int total_threads = N_INT + N_BND;        // 446976 = 1746 * 256 exactly
  int block = 256;
  int grid = total_threads / block;         // 1746
  median5x5_kernel<<<grid, block, 0, stream>>>(x, out);
}

// Round 9
// 38.462 us; speedup vs baseline: 1.0286x; 1.0286x over previous
//
#include <hip/hip_runtime.h>

// 5x5 median, reflect padding, NHWC f32 (16,384,384,3).
// Interior thread = 2 flat columns (f, f+1; f even) x RUN=6 rows, processed as
// 3 PAIRED phases: outputs (h, h+1) share 4 of 5 window rows -> per-column
// SORT4 of common rows computed ONCE; each output rank-inserts its private row
// (h-2 for first, h+3 for second) via closed forms. [math validated R2-R7]
//   - Taps at stride C=3: {f-6,f-3,f,f+3,f+6}; pair spans 14 floats = 7 float2.
//   - 6-slot ring of sorted 5-windows per column, hard-coded rotation:
//     slot(r) = (r - h0 + 2) mod 6.
// __launch_bounds__(256,2): free the allocator (R6/R7: 56 VGPR -> serialized
// schedule + mov padding; ~291 issued insts/output vs ~182 math).
// Border columns (flat 0..5, 1146..1151) in dedicated trailing blocks.

#define CAS(a, b) do { float _t = fminf(a, b); (b) = fmaxf(a, b); (a) = _t; } while (0)

#define SORT5(e0, e1, e2, e3, e4) do { \
  CAS(e0, e1); CAS(e3, e4); CAS(e2, e4); CAS(e2, e3); CAS(e1, e4); \
  CAS(e0, e3); CAS(e0, e2); CAS(e1, e3); CAS(e1, e2); } while (0)

#define SORT4(a, b, c, d) do { \
  CAS(a, b); CAS(c, d); CAS(a, c); CAS(b, d); CAS(b, c); } while (0)

__device__ __forceinline__ int reflect_idx(int v, int n) {
  v = v < 0 ? -v : v;
  v = v >= n ? 2 * n - 2 - v : v;
  return v;
}

#define SORT_TO(P, e0, e1, e2, e3, e4) do { \
  SORT5(e0, e1, e2, e3, e4); \
  P##0 = e0; P##1 = e1; P##2 = e2; P##3 = e3; P##4 = e4; } while (0)

// Rank-7-of-13 band selection; consumes locals A1..E2 (mutating), writes dst.
#define BANDSEL(dst) do { \
  CAS(B3, Cx3); CAS(A1, B1); CAS(A1, Cx1); \
  CAS(A2, B3); CAS(Cx2, D2); CAS(B3, D2); \
  CAS(B1, Cx1); CAS(D1, A2); CAS(B1, D1); \
  float s0=Cx1,s1=B2,s2=B3,s3=Cx2,s4=A2,s5=D1,s6=D3,s7=E1; \
  CAS(s0, s1); CAS(s2, s3); CAS(s4, s5); CAS(s6, s7); \
  CAS(s0, s2); CAS(s4, s6); CAS(s0, s4); \
  CAS(s1, s3); CAS(s5, s7); CAS(s3, s7); \
  float t0=s1,t1=s2,t2=s3,t3=s4,t4=s5,t5=s6,t6=E2; \
  CAS(t0, t1); CAS(t2, t3); CAS(t4, t5); \
  CAS(t0, t2); CAS(t0, t4); CAS(t0, t6); \
  CAS(t1, t3); CAS(t5, t6); CAS(t3, t6); \
  CAS(t1, t2); CAS(t3, t4); \
  CAS(t1, t3); CAS(t1, t5); \
  CAS(t2, t4); CAS(t4, t5); \
  CAS(t2, t3); \
  dst = fmaxf(t2, fminf(t3, t4)); \
} while (0)

// Paired exact median-of-25: S0..S3 = the 4 COMMON sorted rows (any order),
// IA = first output's private sorted row, IB = second's. Shares the SORT4s.
#define MED25_PAIR(dA, dB, S0, S1, S2, S3, IA, IB) do { \
  float pp0=S0##0,qq0=S1##0,rr0=S2##0,ss0=S3##0; SORT4(pp0,qq0,rr0,ss0); \
  float pp1=S0##1,qq1=S1##1,rr1=S2##1,ss1=S3##1; SORT4(pp1,qq1,rr1,ss1); \
  float pp2=S0##2,qq2=S1##2,rr2=S2##2,ss2=S3##2; SORT4(pp2,qq2,rr2,ss2); \
  float pp3=S0##3,qq3=S1##3,rr3=S2##3,ss3=S3##3; SORT4(pp3,qq3,rr3,ss3); \
  float pp4=S0##4,qq4=S1##4,rr4=S2##4,ss4=S3##4; SORT4(pp4,qq4,rr4,ss4); \
  { float D1=fmaxf(rr0,fminf(ss0,IA##0)), E1=fmaxf(ss0,IA##0); \
    float Cx1=fmaxf(qq1,fminf(rr1,IA##1)), D2=fmaxf(rr1,fminf(ss1,IA##1)), E2=fmaxf(ss1,IA##1); \
    float B1=fmaxf(pp2,fminf(qq2,IA##2)), Cx2=fmaxf(qq2,fminf(rr2,IA##2)), D3=fmaxf(rr2,fminf(ss2,IA##2)); \
    float A1=fminf(pp3,IA##3), B2=fminf(qq3,fmaxf(pp3,IA##3)), Cx3=fminf(rr3,fmaxf(qq3,IA##3)); \
    float A2=fminf(pp4,IA##4), B3=fminf(qq4,fmaxf(pp4,IA##4)); \
    BANDSEL(dA); } \
  { float D1=fmaxf(rr0,fminf(ss0,IB##0)), E1=fmaxf(ss0,IB##0); \
    float Cx1=fmaxf(qq1,fminf(rr1,IB##1)), D2=fmaxf(rr1,fminf(ss1,IB##1)), E2=fmaxf(ss1,IB##1); \
    float B1=fmaxf(pp2,fminf(qq2,IB##2)), Cx2=fmaxf(qq2,fminf(rr2,IB##2)), D3=fmaxf(rr2,fminf(ss2,IB##2)); \
    float A1=fminf(pp3,IB##3), B2=fminf(qq3,fmaxf(pp3,IB##3)), Cx3=fminf(rr3,fmaxf(qq3,IB##3)); \
    float A2=fminf(pp4,IB##4), B3=fminf(qq4,fmaxf(pp4,IB##4)); \
    BANDSEL(dB); } \
} while (0)

constexpr int RUN = 6;
constexpr int Bn = 16, Hn = 384, Wn = 384, Cn = 3;
constexpr int WC = Wn * Cn;              // 1152
constexpr int HB = Hn / RUN;             // 64
constexpr int NG_I = 570;                // pairs (f, f+1), f = 6 + 2*gi
constexpr int N_INT = Bn * HB * NG_I;    // 583680 = 2280 * 256
constexpr int N_BND = Bn * HB * 12;      // 12288  = 48 * 256

// Load row RR (absolute h) into the 7 named float2 regs.
#define LOADROW(V0,V1,V2,V3,V4,V5,V6, RR) do { \
  const float2* rp = reinterpret_cast<const float2*>(xb + reflect_idx((RR), Hn) * WC); \
  V0=rp[0]; V1=rp[1]; V2=rp[2]; V3=rp[3]; V4=rp[4]; V5=rp[5]; V6=rp[6]; } while (0)

// Sort the 7-float2 raw row into ring slots PA (col f) / PB (col f+1).
#define SORTROW(V0,V1,V2,V3,V4,V5,V6, PA, PB) do { \
  float e0=V0.x,e1=V1.y,e2=V3.x,e3=V4.y,e4=V6.x; \
  float g0=V0.y,g1=V2.x,g2=V3.y,g3=V5.x,g4=V6.y; \
  SORT_TO(PA, e0, e1, e2, e3, e4); \
  SORT_TO(PB, g0, g1, g2, g3, g4); } while (0)

__global__ __launch_bounds__(256, 2) void median5x5_kernel(
    const float* __restrict__ x, float* __restrict__ out) {
  int t = blockIdx.x * blockDim.x + threadIdx.x;

  if (t < N_INT) {
    // ---------------- interior fast path ----------------
    int gi = t % NG_I;
    int rest = t / NG_I;
    int hb = rest % HB;
    int b = rest / HB;
    int h0 = hb * RUN;
    int f = 6 + 2 * gi;

    const float* xb = x + b * Hn * WC + (f - 6);

    // 6-slot ring x 5 sorted elems x 2 cols; slot(r) = (r - h0 + 2) mod 6
    float a00,a01,a02,a03,a04, a10,a11,a12,a13,a14, a20,a21,a22,a23,a24,
          a30,a31,a32,a33,a34, a40,a41,a42,a43,a44, a50,a51,a52,a53,a54;
    float b00,b01,b02,b03,b04, b10,b11,b12,b13,b14, b20,b21,b22,b23,b24,
          b30,b31,b32,b33,b34, b40,b41,b42,b43,b44, b50,b51,b52,b53,b54;

    float2 v0, v1, v2, v3, v4, v5, v6;   // prefetch row A
    float2 u0, u1, u2, u3, u4, u5, u6;   // prefetch row B

    // prologue: rows h0-2..h0+1 -> slots 0..3
    LOADROW(v0,v1,v2,v3,v4,v5,v6, h0 - 2); SORTROW(v0,v1,v2,v3,v4,v5,v6, a0, b0);
    LOADROW(v0,v1,v2,v3,v4,v5,v6, h0 - 1); SORTROW(v0,v1,v2,v3,v4,v5,v6, a1, b1);
    LOADROW(v0,v1,v2,v3,v4,v5,v6, h0    ); SORTROW(v0,v1,v2,v3,v4,v5,v6, a2, b2);
    LOADROW(v0,v1,v2,v3,v4,v5,v6, h0 + 1); SORTROW(v0,v1,v2,v3,v4,v5,v6, a3, b3);

    // prefetch rows h0+2, h0+3
    LOADROW(v0,v1,v2,v3,v4,v5,v6, h0 + 2);
    LOADROW(u0,u1,u2,u3,u4,u5,u6, h0 + 3);

    int orow = (b * Hn + h0) * WC + f;

    // ---- phase 0: outputs h0, h0+1 ----
    SORTROW(v0,v1,v2,v3,v4,v5,v6, a4, b4);   // row h0+2 -> slot 4
    SORTROW(u0,u1,u2,u3,u4,u5,u6, a5, b5);   // row h0+3 -> slot 5
    LOADROW(v0,v1,v2,v3,v4,v5,v6, h0 + 4);
    LOADROW(u0,u1,u2,u3,u4,u5,u6, h0 + 5);
    {
      float2 oA, oB;
      MED25_PAIR(oA.x, oB.x, a1, a2, a3, a4, a0, a5);
      MED25_PAIR(oA.y, oB.y, b1, b2, b3, b4, b0, b5);
      *reinterpret_cast<float2*>(out + orow         ) = oA;
      *reinterpret_cast<float2*>(out + orow + 1 * WC) = oB;
    }

    // ---- phase 1: outputs h0+2, h0+3 ----
    SORTROW(v0,v1,v2,v3,v4,v5,v6, a0, b0);   // row h0+4 -> slot 0
    SORTROW(u0,u1,u2,u3,u4,u5,u6, a1, b1);   // row h0+5 -> slot 1
    LOADROW(v0,v1,v2,v3,v4,v5,v6, h0 + 6);
    LOADROW(u0,u1,u2,u3,u4,u5,u6, h0 + 7);
    {
      float2 oA, oB;
      MED25_PAIR(oA.x, oB.x, a3, a4, a5, a0, a2, a1);
      MED25_PAIR(oA.y, oB.y, b3, b4, b5, b0, b2, b1);
      *reinterpret_cast<float2*>(out + orow + 2 * WC) = oA;
      *reinterpret_cast<float2*>(out + orow + 3 * WC) = oB;
    }

    // ---- phase 2: outputs h0+4, h0+5 ----
    SORTROW(v0,v1,v2,v3,v4,v5,v6, a2, b2);   // row h0+6 -> slot 2
    SORTROW(u0,u1,u2,u3,u4,u5,u6, a3, b3);   // row h0+7 -> slot 3
    {
      float2 oA, oB;
      MED25_PAIR(oA.x, oB.x, a5, a0, a1, a2, a4, a3);
      MED25_PAIR(oA.y, oB.y, b5, b0, b1, b2, b4, b3);
      *reinterpret_cast<float2*>(out + orow + 4 * WC) = oA;
      *reinterpret_cast<float2*>(out + orow + 5 * WC) = oB;
    }
  } else {
    // ---------------- border columns (w reflection) ----------------
    int u = t - N_INT;
    int col = u % 12;
    int rest = u / 12;
    int hb = rest % HB;
    int b = rest / HB;
    int h0 = hb * RUN;
    int f = col < 6 ? col : (WC - 12 + col);   // 0..5 or 1146..1151
    int w = f / 3, c = f % 3;

    int o0 = reflect_idx(w - 2, Wn) * 3 + c;
    int o1 = reflect_idx(w - 1, Wn) * 3 + c;
    int o2 = w * 3 + c;
    int o3 = reflect_idx(w + 1, Wn) * 3 + c;
    int o4 = reflect_idx(w + 2, Wn) * 3 + c;

    const float* xb = x + b * Hn * WC;

    // 6-slot ring, single column
    float a00,a01,a02,a03,a04, a10,a11,a12,a13,a14, a20,a21,a22,a23,a24,
          a30,a31,a32,a33,a34, a40,a41,a42,a43,a44, a50,a51,a52,a53,a54;

#define BLOAD_SORT(RR, AN) do { \
    const float* rp = xb + reflect_idx((RR), Hn) * WC; \
    float e0=rp[o0], e1=rp[o1], e2=rp[o2], e3=rp[o3], e4=rp[o4]; \
    SORT_TO(AN, e0, e1, e2, e3, e4); } while (0)

    BLOAD_SORT(h0 - 2, a0); BLOAD_SORT(h0 - 1, a1);
    BLOAD_SORT(h0    , a2); BLOAD_SORT(h0 + 1, a3);

    int orow = (b * Hn + h0) * WC + f;

    // phase 0: rows h0+2,h0+3 -> slots 4,5
    BLOAD_SORT(h0 + 2, a4); BLOAD_SORT(h0 + 3, a5);
    {
      float oA, oB;
      MED25_PAIR(oA, oB, a1, a2, a3, a4, a0, a5);
      out[orow         ] = oA;
      out[orow + 1 * WC] = oB;
    }
    // phase 1: rows h0+4,h0+5 -> slots 0,1
    BLOAD_SORT(h0 + 4, a0); BLOAD_SORT(h0 + 5, a1);
    {
      float oA, oB;
      MED25_PAIR(oA, oB, a3, a4, a5, a0, a2, a1);
      out[orow + 2 * WC] = oA;
      out[orow + 3 * WC] = oB;
    }
    // phase 2: rows h0+6,h0+7 -> slots 2,3
    BLOAD_SORT(h0 + 6, a2); BLOAD_SORT(h0 + 7, a3);
    {
      float oA, oB;
      MED25_PAIR(oA, oB, a5, a0, a1, a2, a4, a3);
      out[orow + 4 * WC] = oA;
      out[orow + 5 * WC] = oB;
    }
  }
}

extern "C" void kernel_launch(void* const* d_in, const int* in_sizes, int n_in,
                              void* d_out, int out_size, void* d_ws, size_t ws_size,
                              hipStream_t stream) {
  const float* x = (const float*)d_in[0];
  float* out = (float*)d_out;
  int total_threads = N_INT + N_BND;        // 595968 = 2328 * 256 exactly
  int block = 256;
  int grid = total_threads / block;         // 2328
  median5x5_kernel<<<grid, block, 0, stream>>>(x, out);
}